// Round 14
// baseline (195.850 us; speedup 1.0000x reference)
//
#include <hip/hip_runtime.h>

#define NN 50000      // nodes
#define NE 160000     // graph edges
#define NP 100000     // pos (=neg) edges
#define DIN 512
#define DH  256
#define DO  64
#define NBLK_SCAN 196 // ceil(50000/256)

// prep_all block-range partition (weights + deg zero only)
#define PW1_BLKS 1024    // 512*512 / 256
#define PW2_BLKS 128     // 128*256 / 256
#define PWP_BLKS 32      // 64*128 / 256
#define ZDEG_BLKS 196    // 50048 / 256
#define PREP_BLKS (PW1_BLKS + PW2_BLKS + PWP_BLKS + ZDEG_BLKS)

typedef short bf16x8 __attribute__((ext_vector_type(8)));
typedef float f32x4  __attribute__((ext_vector_type(4)));

__device__ __forceinline__ float bf2f(unsigned short u) {
    return __uint_as_float(((unsigned int)u) << 16);
}
__device__ __forceinline__ unsigned short f2bf(float f) {
    unsigned int x = __float_as_uint(f);
    return (unsigned short)((x + 0x7fffu + ((x >> 16) & 1u)) >> 16);
}

__device__ __forceinline__ void gload_lds16(const void* g, void* l) {
    __builtin_amdgcn_global_load_lds(
        (const __attribute__((address_space(1))) void*)g,
        (__attribute__((address_space(3))) void*)l, 16, 0, 0);
}

// ---------------- fused prep: cvt+transpose weights, zero deg ----------
__global__ __launch_bounds__(256) void prep_all(
    const float* __restrict__ Wself1, const float* __restrict__ Wneigh1, unsigned short* __restrict__ Bt1,
    const float* __restrict__ Wself2, const float* __restrict__ Wneigh2, unsigned short* __restrict__ Bt2,
    const float* __restrict__ Wp1, unsigned short* __restrict__ Wp1b,
    int* __restrict__ deg_i)
{
    int blk = blockIdx.x;
    if (blk < PW1_BLKS) {
        int idx = blk * 256 + threadIdx.x;
        int n = idx >> 9, k = idx & 511;
        float v = (n < DH) ? Wself1[(size_t)k * DH + n] : Wneigh1[(size_t)k * DH + (n - DH)];
        Bt1[idx] = f2bf(v);
        return;
    }
    blk -= PW1_BLKS;
    if (blk < PW2_BLKS) {
        int idx = blk * 256 + threadIdx.x;
        int n = idx >> 8, k = idx & 255;
        float v = (n < DO) ? Wself2[(size_t)k * DO + n] : Wneigh2[(size_t)k * DO + (n - DO)];
        Bt2[idx] = f2bf(v);
        return;
    }
    blk -= PW2_BLKS;
    if (blk < PWP_BLKS) {
        int idx = blk * 256 + threadIdx.x;
        int n = idx >> 7, k = idx & 127;
        Wp1b[idx] = f2bf(Wp1[(size_t)k * 64 + n]);
        return;
    }
    blk -= PWP_BLKS;
    {
        int i = blk * 256 + threadIdx.x;
        if (i < 50048) deg_i[i] = 0;
    }
}

// ---------------- CSR build ----------------
__global__ __launch_bounds__(256) void deg_count(const int* __restrict__ dst, int* __restrict__ deg) {
    int e = blockIdx.x * 256 + threadIdx.x;
    if (e < NE) atomicAdd(&deg[dst[e]], 1);
}

__global__ __launch_bounds__(256) void scan_part(const int* __restrict__ deg, int* __restrict__ excl,
                                                 int* __restrict__ bsums) {
    __shared__ int sh[256];
    int i = blockIdx.x * 256 + threadIdx.x;
    int v = (i < NN) ? deg[i] : 0;
    sh[threadIdx.x] = v;
    __syncthreads();
    #pragma unroll
    for (int off = 1; off < 256; off <<= 1) {
        int t = (threadIdx.x >= off) ? sh[threadIdx.x - off] : 0;
        __syncthreads();
        sh[threadIdx.x] += t;
        __syncthreads();
    }
    if (i < NN) excl[i] = sh[threadIdx.x] - v;
    if (threadIdx.x == 255) bsums[blockIdx.x] = sh[255];
}

__global__ __launch_bounds__(256) void scan_sums(int* __restrict__ bsums, int* __restrict__ boff) {
    __shared__ int sh[256];
    int v = (threadIdx.x < NBLK_SCAN) ? bsums[threadIdx.x] : 0;
    sh[threadIdx.x] = v;
    __syncthreads();
    #pragma unroll
    for (int off = 1; off < 256; off <<= 1) {
        int t = (threadIdx.x >= off) ? sh[threadIdx.x - off] : 0;
        __syncthreads();
        sh[threadIdx.x] += t;
        __syncthreads();
    }
    boff[threadIdx.x] = sh[threadIdx.x] - v;
}

__global__ __launch_bounds__(256) void scan_add(int* __restrict__ off, const int* __restrict__ boff,
                                                int* __restrict__ cursor) {
    int i = blockIdx.x * 256 + threadIdx.x;
    if (i < NN) {
        int o = off[i] + boff[blockIdx.x];
        off[i] = o;
        cursor[i] = o;
    }
    if (i == 0) off[NN] = NE;
}

__global__ __launch_bounds__(256) void fill_csr(const int* __restrict__ src, const int* __restrict__ dst,
                                                int* __restrict__ cursor, int* __restrict__ eidx) {
    int e = blockIdx.x * 256 + threadIdx.x;
    if (e < NE) {
        int p = atomicAdd(&cursor[dst[e]], 1);
        eidx[p] = src[e];
    }
}

// ---------------- layer-1 GEMM: C = cvt_bf16(x_f32) @ Bt1^T ------------------
// R9's proven dataflow (sync1 -> B gload_lds + A cvt/ds_write -> sync2 -> pa
// prefetch -> MFMA), tile grown to BM=256 x BN=128 with 8 waves: each barrier
// drain now covers 2x the MFMA work. Per-wave shape (64x64, acc 4x4) and
// staging pattern identical to R9. 1D grid + bijective XCD swizzle (m204).
__global__ __launch_bounds__(512) void gemm_xf32(
    const float* __restrict__ A, const unsigned short* __restrict__ Bt,
    unsigned short* __restrict__ Cout, int M, int N, int K)
{
    __shared__ unsigned short As[256 * 64];   // 32 KB, chunk-XOR swizzle
    __shared__ unsigned short Bs[128 * 64];   // 16 KB
    const int tid = threadIdx.x;
    const int w = tid >> 6, l = tid & 63;
    const int wr = (w >> 1) * 64, wc = (w & 1) * 64;   // 4x2 wave grid, 64x64 each

    const int nwg = gridDim.x, gx = N >> 7;
    const int q = nwg >> 3, r = nwg & 7;
    const int xcd = blockIdx.x & 7, pos = blockIdx.x >> 3;
    const int work = (xcd < r ? xcd * (q + 1) : r * (q + 1) + (xcd - r) * q) + pos;
    const int row0 = (work / gx) * 256, col0 = (work % gx) * 128;

    f32x4 acc[4][4];
    #pragma unroll
    for (int i = 0; i < 4; ++i)
        #pragma unroll
        for (int j = 0; j < 4; ++j)
            #pragma unroll
            for (int rr = 0; rr < 4; ++rr) acc[i][j][rr] = 0.0f;

    const int wave_chunk = tid & 448;   // w*64, wave-uniform chunk base

    // per-thread A staging regs: 4 chunks x 8 fp32 (256x64 tile / 512 thr)
    float4 pa[4][2];
    #pragma unroll
    for (int u = 0; u < 4; ++u) {
        int c = u * 512 + tid;
        int row = c >> 3, j = c & 7;
        int grow = row0 + row; if (grow >= M) grow = M - 1;
        const float* s = A + (size_t)grow * K + j * 8;
        pa[u][0] = *(const float4*)s;
        pa[u][1] = *(const float4*)(s + 4);
    }

    for (int k0 = 0; k0 < K; k0 += 64) {
        __syncthreads();
        // B tile: async global->LDS (pre-swizzled source, linear dest), 2 chunks/thread
        #pragma unroll
        for (int u = 0; u < 2; ++u) {
            int c = u * 512 + tid;
            int cn = c >> 3, j = c & 7;
            int js = j ^ (cn & 7);
            gload_lds16(Bt + (size_t)(col0 + cn) * K + k0 + js * 8,
                        (void*)(Bs + (u * 512 + wave_chunk) * 8));
        }
        // A tile: cvt prefetched regs -> swizzled ds_write, 4 chunks/thread
        #pragma unroll
        for (int u = 0; u < 4; ++u) {
            int c = u * 512 + tid;
            int row = c >> 3, j = c & 7;
            int js = j ^ (row & 7);
            union { bf16x8 v; unsigned int u32[4]; } pk;
            asm("v_cvt_pk_bf16_f32 %0, %1, %2" : "=v"(pk.u32[0]) : "v"(pa[u][0].x), "v"(pa[u][0].y));
            asm("v_cvt_pk_bf16_f32 %0, %1, %2" : "=v"(pk.u32[1]) : "v"(pa[u][0].z), "v"(pa[u][0].w));
            asm("v_cvt_pk_bf16_f32 %0, %1, %2" : "=v"(pk.u32[2]) : "v"(pa[u][1].x), "v"(pa[u][1].y));
            asm("v_cvt_pk_bf16_f32 %0, %1, %2" : "=v"(pk.u32[3]) : "v"(pa[u][1].z), "v"(pa[u][1].w));
            *(bf16x8*)&As[row * 64 + js * 8] = pk.v;
        }
        __syncthreads();

        // prefetch next A tile into regs (flies under the MFMA phase)
        if (k0 + 64 < K) {
            #pragma unroll
            for (int u = 0; u < 4; ++u) {
                int c = u * 512 + tid;
                int row = c >> 3, j = c & 7;
                int grow = row0 + row; if (grow >= M) grow = M - 1;
                const float* s = A + (size_t)grow * K + (k0 + 64) + j * 8;
                pa[u][0] = *(const float4*)s;
                pa[u][1] = *(const float4*)(s + 4);
            }
        }

        #pragma unroll
        for (int kk = 0; kk < 2; ++kk) {
            bf16x8 af[4], bfv[4];
            #pragma unroll
            for (int i = 0; i < 4; ++i) {
                int row = wr + i * 16 + (l & 15);
                int ch = (kk * 4 + (l >> 4)) ^ (row & 7);
                af[i] = *(const bf16x8*)&As[row * 64 + ch * 8];
            }
            #pragma unroll
            for (int j = 0; j < 4; ++j) {
                int cc = wc + j * 16 + (l & 15);
                int ch = (kk * 4 + (l >> 4)) ^ (cc & 7);
                bfv[j] = *(const bf16x8*)&Bs[cc * 64 + ch * 8];
            }
            #pragma unroll
            for (int i = 0; i < 4; ++i)
                #pragma unroll
                for (int j = 0; j < 4; ++j)
                    acc[i][j] = __builtin_amdgcn_mfma_f32_16x16x32_bf16(af[i], bfv[j], acc[i][j], 0, 0, 0);
        }
    }

    #pragma unroll
    for (int i = 0; i < 4; ++i) {
        #pragma unroll
        for (int j = 0; j < 4; ++j) {
            int r0 = row0 + wr + i * 16 + ((l >> 4) << 2);
            int c  = col0 + wc + j * 16 + (l & 15);
            #pragma unroll
            for (int rr = 0; rr < 4; ++rr) {
                if (r0 + rr < M)
                    Cout[(size_t)(r0 + rr) * N + c] = f2bf(acc[i][j][rr]);
            }
        }
    }
}

// ---------------- bf16 MFMA GEMM (layer 2): A bf16, Bt bf16, bf16 out --------
__global__ __launch_bounds__(256) void gemm_bf16(
    const unsigned short* __restrict__ A, const unsigned short* __restrict__ Bt,
    unsigned short* __restrict__ Cout, int M, int N, int K)
{
    __shared__ unsigned short As[128 * 64];
    __shared__ unsigned short Bs[128 * 64];
    const int tid = threadIdx.x;
    const int w = tid >> 6, l = tid & 63;
    const int wr = (w >> 1) * 64, wc = (w & 1) * 64;

    const int nwg = gridDim.x, gx = N >> 7;
    const int q = nwg >> 3, r = nwg & 7;
    const int xcd = blockIdx.x & 7, pos = blockIdx.x >> 3;
    const int work = (xcd < r ? xcd * (q + 1) : r * (q + 1) + (xcd - r) * q) + pos;
    const int row0 = (work / gx) * 128, col0 = (work % gx) * 128;

    f32x4 acc[4][4];
    #pragma unroll
    for (int i = 0; i < 4; ++i)
        #pragma unroll
        for (int j = 0; j < 4; ++j)
            #pragma unroll
            for (int rr = 0; rr < 4; ++rr) acc[i][j][rr] = 0.0f;

    const int wave_lds_chunk = (tid & 192) * 8;

    for (int k0 = 0; k0 < K; k0 += 64) {
        __syncthreads();
        #pragma unroll
        for (int u = 0; u < 4; ++u) {
            int c = u * 256 + tid;
            int row = c >> 3, j = c & 7;
            int js = j ^ (row & 7);
            int grow = row0 + row; if (grow >= M) grow = M - 1;
            gload_lds16(A + (size_t)grow * K + k0 + js * 8,
                        (void*)(As + (u * 256) * 8 + wave_lds_chunk));
        }
        #pragma unroll
        for (int u = 0; u < 4; ++u) {
            int c = u * 256 + tid;
            int cn = c >> 3, j = c & 7;
            int js = j ^ (cn & 7);
            gload_lds16(Bt + (size_t)(col0 + cn) * K + k0 + js * 8,
                        (void*)(Bs + (u * 256) * 8 + wave_lds_chunk));
        }
        __syncthreads();

        #pragma unroll
        for (int kk = 0; kk < 2; ++kk) {
            bf16x8 af[4], bfv[4];
            #pragma unroll
            for (int i = 0; i < 4; ++i) {
                int row = wr + i * 16 + (l & 15);
                int ch = (kk * 4 + (l >> 4)) ^ (row & 7);
                af[i] = *(const bf16x8*)&As[row * 64 + ch * 8];
            }
            #pragma unroll
            for (int j = 0; j < 4; ++j) {
                int cc = wc + j * 16 + (l & 15);
                int ch = (kk * 4 + (l >> 4)) ^ (cc & 7);
                bfv[j] = *(const bf16x8*)&Bs[cc * 64 + ch * 8];
            }
            #pragma unroll
            for (int i = 0; i < 4; ++i)
                #pragma unroll
                for (int j = 0; j < 4; ++j)
                    acc[i][j] = __builtin_amdgcn_mfma_f32_16x16x32_bf16(af[i], bfv[j], acc[i][j], 0, 0, 0);
        }
    }

    #pragma unroll
    for (int i = 0; i < 4; ++i) {
        #pragma unroll
        for (int j = 0; j < 4; ++j) {
            int r0 = row0 + wr + i * 16 + ((l >> 4) << 2);
            int c  = col0 + wc + j * 16 + (l & 15);
            #pragma unroll
            for (int rr = 0; rr < 4; ++rr) {
                if (r0 + rr < M)
                    Cout[(size_t)(r0 + rr) * N + c] = f2bf(acc[i][j][rr]);
            }
        }
    }
}

// ---------------- gather-aggregate + combine, layer 1 (bf16 in/out, relu) ----
__global__ __launch_bounds__(256) void agg_combine256(
    const unsigned short* __restrict__ C1, const int* __restrict__ off, const int* __restrict__ eidx,
    const float* __restrict__ b, unsigned short* __restrict__ h1b)
{
    const int wave = threadIdx.x >> 6, lane = threadIdx.x & 63;
    const int n = blockIdx.x * 4 + wave;
    if (n >= NN) return;
    const int e0 = off[n], e1 = off[n + 1];
    float acc0 = 0.f, acc1 = 0.f, acc2 = 0.f, acc3 = 0.f;
    for (int e = e0; e < e1; ++e) {
        int s = eidx[e];
        ushort4 v = *(const ushort4*)&C1[(size_t)s * 512 + 256 + lane * 4];
        acc0 += bf2f(v.x); acc1 += bf2f(v.y); acc2 += bf2f(v.z); acc3 += bf2f(v.w);
    }
    const float rd = (e1 > e0) ? 1.0f / (float)(e1 - e0) : 1.0f;
    ushort4 sv = *(const ushort4*)&C1[(size_t)n * 512 + lane * 4];
    float4 bb = ((const float4*)b)[lane];
    ushort4 o;
    o.x = f2bf(fmaxf(bf2f(sv.x) + acc0 * rd + bb.x, 0.f));
    o.y = f2bf(fmaxf(bf2f(sv.y) + acc1 * rd + bb.y, 0.f));
    o.z = f2bf(fmaxf(bf2f(sv.z) + acc2 * rd + bb.z, 0.f));
    o.w = f2bf(fmaxf(bf2f(sv.w) + acc3 * rd + bb.w, 0.f));
    *(ushort4*)&h1b[(size_t)n * 256 + lane * 4] = o;
}

// ---------------- gather-aggregate + combine, layer 2 (bf16 in, bf16 out) ----
__global__ __launch_bounds__(256) void agg_combine64(
    const unsigned short* __restrict__ C2, const int* __restrict__ off, const int* __restrict__ eidx,
    const float* __restrict__ b, unsigned short* __restrict__ h2b)
{
    const int wave = threadIdx.x >> 6, lane = threadIdx.x & 63;
    const int n = blockIdx.x * 4 + wave;
    if (n >= NN) return;
    const int e0 = off[n], e1 = off[n + 1];
    float acc = 0.f;
    for (int e = e0; e < e1; ++e) {
        int s = eidx[e];
        acc += bf2f(C2[(size_t)s * 128 + 64 + lane]);
    }
    const float rd = (e1 > e0) ? 1.0f / (float)(e1 - e0) : 1.0f;
    h2b[(size_t)n * 64 + lane] = f2bf(bf2f(C2[(size_t)n * 128 + lane]) + acc * rd + b[lane]);
}

// ---------------- edge MLP via MFMA ----------------
__global__ __launch_bounds__(256) void edge_mlp_mfma(
    const unsigned short* __restrict__ h2b,
    const int* __restrict__ psrc, const int* __restrict__ pdst,
    const int* __restrict__ nsrc, const int* __restrict__ ndst,
    const unsigned short* __restrict__ Wp1b, const float* __restrict__ bp1,
    const float* __restrict__ Wp2, const float* __restrict__ bp2,
    float* __restrict__ out)
{
    __shared__ unsigned short z[128 * 128];
    const int tid = threadIdx.x;
    const int w = tid >> 6, l = tid & 63;
    const int e0 = blockIdx.x * 128;

    bf16x8 bfr[4][4];
    #pragma unroll
    for (int kk = 0; kk < 4; ++kk)
        #pragma unroll
        for (int j = 0; j < 4; ++j) {
            int col = j * 16 + (l & 15);
            int ch  = kk * 4 + (l >> 4);
            bfr[kk][j] = *(const bf16x8*)(Wp1b + col * 128 + ch * 8);
        }

    #pragma unroll
    for (int p = 0; p < 8; ++p) {
        int rho = p * 32 + (tid >> 3);
        int c   = tid & 7;
        int r   = rho >> 1;
        int ep  = rho & 1;
        int e   = e0 + r; if (e >= 2 * NP) e = 2 * NP - 1;
        int node = (e < NP) ? (ep ? pdst[e] : psrc[e])
                            : (ep ? ndst[e - NP] : nsrc[e - NP]);
        bf16x8 v = *(const bf16x8*)(h2b + (size_t)node * 64 + c * 8);
        int j = ep * 8 + c;
        *(bf16x8*)&z[r * 128 + ((j ^ (r & 15)) * 8)] = v;
    }
    __syncthreads();

    f32x4 acc[2][4];
    #pragma unroll
    for (int i = 0; i < 2; ++i)
        #pragma unroll
        for (int j = 0; j < 4; ++j)
            #pragma unroll
            for (int rr = 0; rr < 4; ++rr) acc[i][j][rr] = 0.0f;

    #pragma unroll
    for (int kk = 0; kk < 4; ++kk) {
        bf16x8 af[2];
        #pragma unroll
        for (int i = 0; i < 2; ++i) {
            int row = w * 32 + i * 16 + (l & 15);
            int ch  = (kk * 4 + (l >> 4)) ^ (row & 15);
            af[i] = *(const bf16x8*)&z[row * 128 + ch * 8];
        }
        #pragma unroll
        for (int i = 0; i < 2; ++i)
            #pragma unroll
            for (int j = 0; j < 4; ++j)
                acc[i][j] = __builtin_amdgcn_mfma_f32_16x16x32_bf16(af[i], bfr[kk][j], acc[i][j], 0, 0, 0);
    }

    float bp1v[4], w2v[4];
    #pragma unroll
    for (int j = 0; j < 4; ++j) {
        bp1v[j] = bp1[j * 16 + (l & 15)];
        w2v[j]  = Wp2[j * 16 + (l & 15)];
    }
    const float b2v = bp2[0];
    #pragma unroll
    for (int i = 0; i < 2; ++i) {
        #pragma unroll
        for (int rr = 0; rr < 4; ++rr) {
            float p = 0.f;
            #pragma unroll
            for (int j = 0; j < 4; ++j) {
                float h = fmaxf(acc[i][j][rr] + bp1v[j], 0.f);
                p = fmaf(h, w2v[j], p);
            }
            #pragma unroll
            for (int off = 8; off > 0; off >>= 1)
                p += __shfl_xor(p, off, 64);
            int row = w * 32 + i * 16 + ((l >> 4) << 2) + rr;
            if ((l & 15) == 0 && e0 + row < 2 * NP)
                out[e0 + row] = p + b2v;
        }
    }
}

extern "C" void kernel_launch(void* const* d_in, const int* in_sizes, int n_in,
                              void* d_out, int out_size, void* d_ws, size_t ws_size,
                              hipStream_t stream) {
    (void)in_sizes; (void)n_in; (void)out_size; (void)ws_size;
    const float* x       = (const float*)d_in[0];
    const int*   esrc    = (const int*)d_in[1];
    const int*   edst    = (const int*)d_in[2];
    const int*   psrc    = (const int*)d_in[3];
    const int*   pdst    = (const int*)d_in[4];
    const int*   nsrc    = (const int*)d_in[5];
    const int*   ndst    = (const int*)d_in[6];
    const float* Wself1  = (const float*)d_in[7];
    const float* Wneigh1 = (const float*)d_in[8];
    const float* b1      = (const float*)d_in[9];
    const float* Wself2  = (const float*)d_in[10];
    const float* Wneigh2 = (const float*)d_in[11];
    const float* b2      = (const float*)d_in[12];
    const float* Wp1     = (const float*)d_in[13];
    const float* bp1     = (const float*)d_in[14];
    const float* Wp2     = (const float*)d_in[15];
    const float* bp2     = (const float*)d_in[16];
    float* out = (float*)d_out;

    // -------- workspace carve-up --------
    char* w = (char*)d_ws;
    int* deg_i  = (int*)w; w += 50048 * 4;
    int* off    = (int*)w; w += 50052 * 4;
    int* cursor = (int*)w; w += 50048 * 4;
    int* bsums  = (int*)w; w += 256 * 4;
    int* boff   = (int*)w; w += 256 * 4;
    int* eidx   = (int*)w; w += 160000 * 4;
    unsigned short* Bt1  = (unsigned short*)w; w += (size_t)512 * 512 * 2;
    unsigned short* Bt2  = (unsigned short*)w; w += (size_t)128 * 256 * 2;
    unsigned short* Wp1b = (unsigned short*)w; w += (size_t)64 * 128 * 2;
    unsigned short* h1b  = (unsigned short*)w; w += (size_t)NN * DH * 2;   // 25.6 MB
    unsigned short* h2b  = (unsigned short*)w; w += (size_t)NN * DO * 2;   // 6.4 MB
    unsigned short* C1b  = (unsigned short*)w; w += (size_t)NN * 512 * 2;  // 51.2 MB
    unsigned short* C2b  = C1b;   // C1b dead after agg1; C2b = 12.8 MB bf16

    // -------- fused prep (weights, zero deg) --------
    prep_all<<<PREP_BLKS, 256, 0, stream>>>(Wself1, Wneigh1, Bt1,
                                            Wself2, Wneigh2, Bt2, Wp1, Wp1b, deg_i);

    // -------- CSR build --------
    deg_count<<<(NE + 255) / 256, 256, 0, stream>>>(edst, deg_i);
    scan_part<<<NBLK_SCAN, 256, 0, stream>>>(deg_i, off, bsums);
    scan_sums<<<1, 256, 0, stream>>>(bsums, boff);
    scan_add<<<NBLK_SCAN, 256, 0, stream>>>(off, boff, cursor);
    fill_csr<<<(NE + 255) / 256, 256, 0, stream>>>(esrc, edst, cursor, eidx);

    // -------- layer 1: fused cvt+GEMM (BM=256 x BN=128, 8 waves, XCD swizzle) --
    int nwg1 = ((NN + 255) / 256) * (512 / 128);   // 196 * 4 = 784
    gemm_xf32<<<nwg1, 512, 0, stream>>>(x, Bt1, C1b, NN, 512, DIN);
    agg_combine256<<<(NN + 3) / 4, 256, 0, stream>>>(C1b, off, eidx, b1, h1b);

    // -------- layer 2 (bf16 C2) --------
    int nwg2 = (128 / 128) * ((NN + 127) / 128);   // 391
    gemm_bf16<<<nwg2, 256, 0, stream>>>(h1b, Bt2, C2b, NN, 128, DH);
    agg_combine64<<<(NN + 3) / 4, 256, 0, stream>>>(C2b, off, eidx, b2, h2b);

    // -------- edge scorer (MFMA) --------
    edge_mlp_mfma<<<(2 * NP + 127) / 128, 256, 0, stream>>>(h2b, psrc, pdst, nsrc, ndst,
                                                            Wp1b, bp1, Wp2, bp2, out);
}

// Round 15
// 169.812 us; speedup vs baseline: 1.1533x; 1.1533x over previous
//
#include <hip/hip_runtime.h>

#define NN 50000      // nodes
#define NE 160000     // graph edges
#define NP 100000     // pos (=neg) edges
#define DIN 512
#define DH  256
#define DO  64
#define NBLK_SCAN 196 // ceil(50000/256)

// prep_all block-range partition (weights + deg zero only)
#define PW1_BLKS 1024    // 512*512 / 256
#define PW2_BLKS 128     // 128*256 / 256
#define PWP_BLKS 32      // 64*128 / 256
#define ZDEG_BLKS 196    // 50048 / 256
#define PREP_BLKS (PW1_BLKS + PW2_BLKS + PWP_BLKS + ZDEG_BLKS)

typedef short bf16x8 __attribute__((ext_vector_type(8)));
typedef float f32x4  __attribute__((ext_vector_type(4)));

__device__ __forceinline__ float bf2f(unsigned short u) {
    return __uint_as_float(((unsigned int)u) << 16);
}
__device__ __forceinline__ unsigned short f2bf(float f) {
    unsigned int x = __float_as_uint(f);
    return (unsigned short)((x + 0x7fffu + ((x >> 16) & 1u)) >> 16);
}

__device__ __forceinline__ void gload_lds16(const void* g, void* l) {
    __builtin_amdgcn_global_load_lds(
        (const __attribute__((address_space(1))) void*)g,
        (__attribute__((address_space(3))) void*)l, 16, 0, 0);
}

// ---------------- fused prep: cvt+transpose weights, zero deg ----------
__global__ __launch_bounds__(256) void prep_all(
    const float* __restrict__ Wself1, const float* __restrict__ Wneigh1, unsigned short* __restrict__ Bt1,
    const float* __restrict__ Wself2, const float* __restrict__ Wneigh2, unsigned short* __restrict__ Bt2,
    const float* __restrict__ Wp1, unsigned short* __restrict__ Wp1b,
    int* __restrict__ deg_i)
{
    int blk = blockIdx.x;
    if (blk < PW1_BLKS) {
        int idx = blk * 256 + threadIdx.x;
        int n = idx >> 9, k = idx & 511;
        float v = (n < DH) ? Wself1[(size_t)k * DH + n] : Wneigh1[(size_t)k * DH + (n - DH)];
        Bt1[idx] = f2bf(v);
        return;
    }
    blk -= PW1_BLKS;
    if (blk < PW2_BLKS) {
        int idx = blk * 256 + threadIdx.x;
        int n = idx >> 8, k = idx & 255;
        float v = (n < DO) ? Wself2[(size_t)k * DO + n] : Wneigh2[(size_t)k * DO + (n - DO)];
        Bt2[idx] = f2bf(v);
        return;
    }
    blk -= PW2_BLKS;
    if (blk < PWP_BLKS) {
        int idx = blk * 256 + threadIdx.x;
        int n = idx >> 7, k = idx & 127;
        Wp1b[idx] = f2bf(Wp1[(size_t)k * 64 + n]);
        return;
    }
    blk -= PWP_BLKS;
    {
        int i = blk * 256 + threadIdx.x;
        if (i < 50048) deg_i[i] = 0;
    }
}

// ---------------- CSR build ----------------
__global__ __launch_bounds__(256) void deg_count(const int* __restrict__ dst, int* __restrict__ deg) {
    int e = blockIdx.x * 256 + threadIdx.x;
    if (e < NE) atomicAdd(&deg[dst[e]], 1);
}

__global__ __launch_bounds__(256) void scan_part(const int* __restrict__ deg, int* __restrict__ excl,
                                                 int* __restrict__ bsums) {
    __shared__ int sh[256];
    int i = blockIdx.x * 256 + threadIdx.x;
    int v = (i < NN) ? deg[i] : 0;
    sh[threadIdx.x] = v;
    __syncthreads();
    #pragma unroll
    for (int off = 1; off < 256; off <<= 1) {
        int t = (threadIdx.x >= off) ? sh[threadIdx.x - off] : 0;
        __syncthreads();
        sh[threadIdx.x] += t;
        __syncthreads();
    }
    if (i < NN) excl[i] = sh[threadIdx.x] - v;
    if (threadIdx.x == 255) bsums[blockIdx.x] = sh[255];
}

__global__ __launch_bounds__(256) void scan_sums(int* __restrict__ bsums, int* __restrict__ boff) {
    __shared__ int sh[256];
    int v = (threadIdx.x < NBLK_SCAN) ? bsums[threadIdx.x] : 0;
    sh[threadIdx.x] = v;
    __syncthreads();
    #pragma unroll
    for (int off = 1; off < 256; off <<= 1) {
        int t = (threadIdx.x >= off) ? sh[threadIdx.x - off] : 0;
        __syncthreads();
        sh[threadIdx.x] += t;
        __syncthreads();
    }
    boff[threadIdx.x] = sh[threadIdx.x] - v;
}

__global__ __launch_bounds__(256) void scan_add(int* __restrict__ off, const int* __restrict__ boff,
                                                int* __restrict__ cursor) {
    int i = blockIdx.x * 256 + threadIdx.x;
    if (i < NN) {
        int o = off[i] + boff[blockIdx.x];
        off[i] = o;
        cursor[i] = o;
    }
    if (i == 0) off[NN] = NE;
}

__global__ __launch_bounds__(256) void fill_csr(const int* __restrict__ src, const int* __restrict__ dst,
                                                int* __restrict__ cursor, int* __restrict__ eidx) {
    int e = blockIdx.x * 256 + threadIdx.x;
    if (e < NE) {
        int p = atomicAdd(&cursor[dst[e]], 1);
        eidx[p] = src[e];
    }
}

// ---------------- layer-1 GEMM: C = cvt_bf16(x_f32) @ Bt1^T ------------------
// R9-EXACT (best measured: 72 us). m97 barrier structure; A reg-staged fp32
// with cross-phase register prefetch + v_cvt_pk_bf16_f32 + swizzled ds_write;
// B via global_load_lds (pre-swizzled source, linear dest). 1D grid +
// bijective XCD-chunk swizzle (m204).
__global__ __launch_bounds__(256) void gemm_xf32(
    const float* __restrict__ A, const unsigned short* __restrict__ Bt,
    unsigned short* __restrict__ Cout, int M, int N, int K)
{
    __shared__ unsigned short As[128 * 64];
    __shared__ unsigned short Bs[128 * 64];
    const int tid = threadIdx.x;
    const int w = tid >> 6, l = tid & 63;
    const int wr = (w >> 1) * 64, wc = (w & 1) * 64;

    const int nwg = gridDim.x, gx = N >> 7;
    const int q = nwg >> 3, r = nwg & 7;
    const int xcd = blockIdx.x & 7, pos = blockIdx.x >> 3;
    const int work = (xcd < r ? xcd * (q + 1) : r * (q + 1) + (xcd - r) * q) + pos;
    const int row0 = (work / gx) * 128, col0 = (work % gx) * 128;

    f32x4 acc[4][4];
    #pragma unroll
    for (int i = 0; i < 4; ++i)
        #pragma unroll
        for (int j = 0; j < 4; ++j)
            #pragma unroll
            for (int rr = 0; rr < 4; ++rr) acc[i][j][rr] = 0.0f;

    const int wave_lds_chunk = (tid & 192) * 8;

    // per-thread A staging: 4 chunks (u), each 8 floats -> 8 bf16
    float4 pa[4][2];
    #pragma unroll
    for (int u = 0; u < 4; ++u) {
        int c = u * 256 + tid;
        int row = c >> 3, j = c & 7;
        int grow = row0 + row; if (grow >= M) grow = M - 1;
        const float* s = A + (size_t)grow * K + j * 8;
        pa[u][0] = *(const float4*)s;
        pa[u][1] = *(const float4*)(s + 4);
    }

    for (int k0 = 0; k0 < K; k0 += 64) {
        __syncthreads();
        // B tile: async global->LDS (pre-swizzled source, linear dest)
        #pragma unroll
        for (int u = 0; u < 4; ++u) {
            int c = u * 256 + tid;
            int cn = c >> 3, j = c & 7;
            int js = j ^ (cn & 7);
            gload_lds16(Bt + (size_t)(col0 + cn) * K + k0 + js * 8,
                        (void*)(Bs + (u * 256) * 8 + wave_lds_chunk));
        }
        // A tile: cvt prefetched regs -> swizzled ds_write
        #pragma unroll
        for (int u = 0; u < 4; ++u) {
            int c = u * 256 + tid;
            int row = c >> 3, j = c & 7;
            int js = j ^ (row & 7);
            union { bf16x8 v; unsigned int u32[4]; } pk;
            asm("v_cvt_pk_bf16_f32 %0, %1, %2" : "=v"(pk.u32[0]) : "v"(pa[u][0].x), "v"(pa[u][0].y));
            asm("v_cvt_pk_bf16_f32 %0, %1, %2" : "=v"(pk.u32[1]) : "v"(pa[u][0].z), "v"(pa[u][0].w));
            asm("v_cvt_pk_bf16_f32 %0, %1, %2" : "=v"(pk.u32[2]) : "v"(pa[u][1].x), "v"(pa[u][1].y));
            asm("v_cvt_pk_bf16_f32 %0, %1, %2" : "=v"(pk.u32[3]) : "v"(pa[u][1].z), "v"(pa[u][1].w));
            *(bf16x8*)&As[row * 64 + js * 8] = pk.v;
        }
        __syncthreads();

        // prefetch next A tile (flies under the MFMA phase; drained at next sync1)
        if (k0 + 64 < K) {
            #pragma unroll
            for (int u = 0; u < 4; ++u) {
                int c = u * 256 + tid;
                int row = c >> 3, j = c & 7;
                int grow = row0 + row; if (grow >= M) grow = M - 1;
                const float* s = A + (size_t)grow * K + (k0 + 64) + j * 8;
                pa[u][0] = *(const float4*)s;
                pa[u][1] = *(const float4*)(s + 4);
            }
        }

        #pragma unroll
        for (int kk = 0; kk < 2; ++kk) {
            bf16x8 af[4], bfv[4];
            #pragma unroll
            for (int i = 0; i < 4; ++i) {
                int row = wr + i * 16 + (l & 15);
                int ch = (kk * 4 + (l >> 4)) ^ (row & 7);
                af[i] = *(const bf16x8*)&As[row * 64 + ch * 8];
            }
            #pragma unroll
            for (int j = 0; j < 4; ++j) {
                int cc = wc + j * 16 + (l & 15);
                int ch = (kk * 4 + (l >> 4)) ^ (cc & 7);
                bfv[j] = *(const bf16x8*)&Bs[cc * 64 + ch * 8];
            }
            #pragma unroll
            for (int i = 0; i < 4; ++i)
                #pragma unroll
                for (int j = 0; j < 4; ++j)
                    acc[i][j] = __builtin_amdgcn_mfma_f32_16x16x32_bf16(af[i], bfv[j], acc[i][j], 0, 0, 0);
        }
    }

    #pragma unroll
    for (int i = 0; i < 4; ++i) {
        #pragma unroll
        for (int j = 0; j < 4; ++j) {
            int r0 = row0 + wr + i * 16 + ((l >> 4) << 2);
            int c  = col0 + wc + j * 16 + (l & 15);
            #pragma unroll
            for (int rr = 0; rr < 4; ++rr) {
                if (r0 + rr < M)
                    Cout[(size_t)(r0 + rr) * N + c] = f2bf(acc[i][j][rr]);
            }
        }
    }
}

// ---------------- bf16 MFMA GEMM (layer 2): A bf16, Bt bf16, bf16 out --------
__global__ __launch_bounds__(256) void gemm_bf16(
    const unsigned short* __restrict__ A, const unsigned short* __restrict__ Bt,
    unsigned short* __restrict__ Cout, int M, int N, int K)
{
    __shared__ unsigned short As[128 * 64];
    __shared__ unsigned short Bs[128 * 64];
    const int tid = threadIdx.x;
    const int w = tid >> 6, l = tid & 63;
    const int wr = (w >> 1) * 64, wc = (w & 1) * 64;

    const int nwg = gridDim.x, gx = N >> 7;
    const int q = nwg >> 3, r = nwg & 7;
    const int xcd = blockIdx.x & 7, pos = blockIdx.x >> 3;
    const int work = (xcd < r ? xcd * (q + 1) : r * (q + 1) + (xcd - r) * q) + pos;
    const int row0 = (work / gx) * 128, col0 = (work % gx) * 128;

    f32x4 acc[4][4];
    #pragma unroll
    for (int i = 0; i < 4; ++i)
        #pragma unroll
        for (int j = 0; j < 4; ++j)
            #pragma unroll
            for (int rr = 0; rr < 4; ++rr) acc[i][j][rr] = 0.0f;

    const int wave_lds_chunk = (tid & 192) * 8;

    for (int k0 = 0; k0 < K; k0 += 64) {
        __syncthreads();
        #pragma unroll
        for (int u = 0; u < 4; ++u) {
            int c = u * 256 + tid;
            int row = c >> 3, j = c & 7;
            int js = j ^ (row & 7);
            int grow = row0 + row; if (grow >= M) grow = M - 1;
            gload_lds16(A + (size_t)grow * K + k0 + js * 8,
                        (void*)(As + (u * 256) * 8 + wave_lds_chunk));
        }
        #pragma unroll
        for (int u = 0; u < 4; ++u) {
            int c = u * 256 + tid;
            int cn = c >> 3, j = c & 7;
            int js = j ^ (cn & 7);
            gload_lds16(Bt + (size_t)(col0 + cn) * K + k0 + js * 8,
                        (void*)(Bs + (u * 256) * 8 + wave_lds_chunk));
        }
        __syncthreads();

        #pragma unroll
        for (int kk = 0; kk < 2; ++kk) {
            bf16x8 af[4], bfv[4];
            #pragma unroll
            for (int i = 0; i < 4; ++i) {
                int row = wr + i * 16 + (l & 15);
                int ch = (kk * 4 + (l >> 4)) ^ (row & 7);
                af[i] = *(const bf16x8*)&As[row * 64 + ch * 8];
            }
            #pragma unroll
            for (int j = 0; j < 4; ++j) {
                int cc = wc + j * 16 + (l & 15);
                int ch = (kk * 4 + (l >> 4)) ^ (cc & 7);
                bfv[j] = *(const bf16x8*)&Bs[cc * 64 + ch * 8];
            }
            #pragma unroll
            for (int i = 0; i < 4; ++i)
                #pragma unroll
                for (int j = 0; j < 4; ++j)
                    acc[i][j] = __builtin_amdgcn_mfma_f32_16x16x32_bf16(af[i], bfv[j], acc[i][j], 0, 0, 0);
        }
    }

    #pragma unroll
    for (int i = 0; i < 4; ++i) {
        #pragma unroll
        for (int j = 0; j < 4; ++j) {
            int r0 = row0 + wr + i * 16 + ((l >> 4) << 2);
            int c  = col0 + wc + j * 16 + (l & 15);
            #pragma unroll
            for (int rr = 0; rr < 4; ++rr) {
                if (r0 + rr < M)
                    Cout[(size_t)(r0 + rr) * N + c] = f2bf(acc[i][j][rr]);
            }
        }
    }
}

// ---------------- gather-aggregate + combine, layer 1 (bf16 in/out, relu) ----
// unroll-2 edge loop: 2 independent gathers in flight on the latency chain
__global__ __launch_bounds__(256) void agg_combine256(
    const unsigned short* __restrict__ C1, const int* __restrict__ off, const int* __restrict__ eidx,
    const float* __restrict__ b, unsigned short* __restrict__ h1b)
{
    const int wave = threadIdx.x >> 6, lane = threadIdx.x & 63;
    const int n = blockIdx.x * 4 + wave;
    if (n >= NN) return;
    const int e0 = off[n], e1 = off[n + 1];
    float acc0 = 0.f, acc1 = 0.f, acc2 = 0.f, acc3 = 0.f;
    int e = e0;
    for (; e + 1 < e1; e += 2) {
        int s0 = eidx[e], s1 = eidx[e + 1];
        ushort4 v0 = *(const ushort4*)&C1[(size_t)s0 * 512 + 256 + lane * 4];
        ushort4 v1 = *(const ushort4*)&C1[(size_t)s1 * 512 + 256 + lane * 4];
        acc0 += bf2f(v0.x) + bf2f(v1.x);
        acc1 += bf2f(v0.y) + bf2f(v1.y);
        acc2 += bf2f(v0.z) + bf2f(v1.z);
        acc3 += bf2f(v0.w) + bf2f(v1.w);
    }
    if (e < e1) {
        int s0 = eidx[e];
        ushort4 v0 = *(const ushort4*)&C1[(size_t)s0 * 512 + 256 + lane * 4];
        acc0 += bf2f(v0.x); acc1 += bf2f(v0.y); acc2 += bf2f(v0.z); acc3 += bf2f(v0.w);
    }
    const float rd = (e1 > e0) ? 1.0f / (float)(e1 - e0) : 1.0f;
    ushort4 sv = *(const ushort4*)&C1[(size_t)n * 512 + lane * 4];
    float4 bb = ((const float4*)b)[lane];
    ushort4 o;
    o.x = f2bf(fmaxf(bf2f(sv.x) + acc0 * rd + bb.x, 0.f));
    o.y = f2bf(fmaxf(bf2f(sv.y) + acc1 * rd + bb.y, 0.f));
    o.z = f2bf(fmaxf(bf2f(sv.z) + acc2 * rd + bb.z, 0.f));
    o.w = f2bf(fmaxf(bf2f(sv.w) + acc3 * rd + bb.w, 0.f));
    *(ushort4*)&h1b[(size_t)n * 256 + lane * 4] = o;
}

// ---------------- gather-aggregate + combine, layer 2 (bf16 in, bf16 out) ----
__global__ __launch_bounds__(256) void agg_combine64(
    const unsigned short* __restrict__ C2, const int* __restrict__ off, const int* __restrict__ eidx,
    const float* __restrict__ b, unsigned short* __restrict__ h2b)
{
    const int wave = threadIdx.x >> 6, lane = threadIdx.x & 63;
    const int n = blockIdx.x * 4 + wave;
    if (n >= NN) return;
    const int e0 = off[n], e1 = off[n + 1];
    float acc = 0.f;
    int e = e0;
    for (; e + 1 < e1; e += 2) {
        int s0 = eidx[e], s1 = eidx[e + 1];
        float v0 = bf2f(C2[(size_t)s0 * 128 + 64 + lane]);
        float v1 = bf2f(C2[(size_t)s1 * 128 + 64 + lane]);
        acc += v0 + v1;
    }
    if (e < e1) acc += bf2f(C2[(size_t)eidx[e] * 128 + 64 + lane]);
    const float rd = (e1 > e0) ? 1.0f / (float)(e1 - e0) : 1.0f;
    h2b[(size_t)n * 64 + lane] = f2bf(bf2f(C2[(size_t)n * 128 + lane]) + acc * rd + b[lane]);
}

// ---------------- edge MLP via MFMA ----------------
__global__ __launch_bounds__(256) void edge_mlp_mfma(
    const unsigned short* __restrict__ h2b,
    const int* __restrict__ psrc, const int* __restrict__ pdst,
    const int* __restrict__ nsrc, const int* __restrict__ ndst,
    const unsigned short* __restrict__ Wp1b, const float* __restrict__ bp1,
    const float* __restrict__ Wp2, const float* __restrict__ bp2,
    float* __restrict__ out)
{
    __shared__ unsigned short z[128 * 128];
    const int tid = threadIdx.x;
    const int w = tid >> 6, l = tid & 63;
    const int e0 = blockIdx.x * 128;

    bf16x8 bfr[4][4];
    #pragma unroll
    for (int kk = 0; kk < 4; ++kk)
        #pragma unroll
        for (int j = 0; j < 4; ++j) {
            int col = j * 16 + (l & 15);
            int ch  = kk * 4 + (l >> 4);
            bfr[kk][j] = *(const bf16x8*)(Wp1b + col * 128 + ch * 8);
        }

    #pragma unroll
    for (int p = 0; p < 8; ++p) {
        int rho = p * 32 + (tid >> 3);
        int c   = tid & 7;
        int r   = rho >> 1;
        int ep  = rho & 1;
        int e   = e0 + r; if (e >= 2 * NP) e = 2 * NP - 1;
        int node = (e < NP) ? (ep ? pdst[e] : psrc[e])
                            : (ep ? ndst[e - NP] : nsrc[e - NP]);
        bf16x8 v = *(const bf16x8*)(h2b + (size_t)node * 64 + c * 8);
        int j = ep * 8 + c;
        *(bf16x8*)&z[r * 128 + ((j ^ (r & 15)) * 8)] = v;
    }
    __syncthreads();

    f32x4 acc[2][4];
    #pragma unroll
    for (int i = 0; i < 2; ++i)
        #pragma unroll
        for (int j = 0; j < 4; ++j)
            #pragma unroll
            for (int rr = 0; rr < 4; ++rr) acc[i][j][rr] = 0.0f;

    #pragma unroll
    for (int kk = 0; kk < 4; ++kk) {
        bf16x8 af[2];
        #pragma unroll
        for (int i = 0; i < 2; ++i) {
            int row = w * 32 + i * 16 + (l & 15);
            int ch  = (kk * 4 + (l >> 4)) ^ (row & 15);
            af[i] = *(const bf16x8*)&z[row * 128 + ch * 8];
        }
        #pragma unroll
        for (int i = 0; i < 2; ++i)
            #pragma unroll
            for (int j = 0; j < 4; ++j)
                acc[i][j] = __builtin_amdgcn_mfma_f32_16x16x32_bf16(af[i], bfr[kk][j], acc[i][j], 0, 0, 0);
    }

    float bp1v[4], w2v[4];
    #pragma unroll
    for (int j = 0; j < 4; ++j) {
        bp1v[j] = bp1[j * 16 + (l & 15)];
        w2v[j]  = Wp2[j * 16 + (l & 15)];
    }
    const float b2v = bp2[0];
    #pragma unroll
    for (int i = 0; i < 2; ++i) {
        #pragma unroll
        for (int rr = 0; rr < 4; ++rr) {
            float p = 0.f;
            #pragma unroll
            for (int j = 0; j < 4; ++j) {
                float h = fmaxf(acc[i][j][rr] + bp1v[j], 0.f);
                p = fmaf(h, w2v[j], p);
            }
            #pragma unroll
            for (int off = 8; off > 0; off >>= 1)
                p += __shfl_xor(p, off, 64);
            int row = w * 32 + i * 16 + ((l >> 4) << 2) + rr;
            if ((l & 15) == 0 && e0 + row < 2 * NP)
                out[e0 + row] = p + b2v;
        }
    }
}

extern "C" void kernel_launch(void* const* d_in, const int* in_sizes, int n_in,
                              void* d_out, int out_size, void* d_ws, size_t ws_size,
                              hipStream_t stream) {
    (void)in_sizes; (void)n_in; (void)out_size; (void)ws_size;
    const float* x       = (const float*)d_in[0];
    const int*   esrc    = (const int*)d_in[1];
    const int*   edst    = (const int*)d_in[2];
    const int*   psrc    = (const int*)d_in[3];
    const int*   pdst    = (const int*)d_in[4];
    const int*   nsrc    = (const int*)d_in[5];
    const int*   ndst    = (const int*)d_in[6];
    const float* Wself1  = (const float*)d_in[7];
    const float* Wneigh1 = (const float*)d_in[8];
    const float* b1      = (const float*)d_in[9];
    const float* Wself2  = (const float*)d_in[10];
    const float* Wneigh2 = (const float*)d_in[11];
    const float* b2      = (const float*)d_in[12];
    const float* Wp1     = (const float*)d_in[13];
    const float* bp1     = (const float*)d_in[14];
    const float* Wp2     = (const float*)d_in[15];
    const float* bp2     = (const float*)d_in[16];
    float* out = (float*)d_out;

    // -------- workspace carve-up --------
    char* w = (char*)d_ws;
    int* deg_i  = (int*)w; w += 50048 * 4;
    int* off    = (int*)w; w += 50052 * 4;
    int* cursor = (int*)w; w += 50048 * 4;
    int* bsums  = (int*)w; w += 256 * 4;
    int* boff   = (int*)w; w += 256 * 4;
    int* eidx   = (int*)w; w += 160000 * 4;
    unsigned short* Bt1  = (unsigned short*)w; w += (size_t)512 * 512 * 2;
    unsigned short* Bt2  = (unsigned short*)w; w += (size_t)128 * 256 * 2;
    unsigned short* Wp1b = (unsigned short*)w; w += (size_t)64 * 128 * 2;
    unsigned short* h1b  = (unsigned short*)w; w += (size_t)NN * DH * 2;   // 25.6 MB
    unsigned short* h2b  = (unsigned short*)w; w += (size_t)NN * DO * 2;   // 6.4 MB
    unsigned short* C1b  = (unsigned short*)w; w += (size_t)NN * 512 * 2;  // 51.2 MB
    unsigned short* C2b  = C1b;   // C1b dead after agg1; C2b = 12.8 MB bf16

    // -------- fused prep (weights, zero deg) --------
    prep_all<<<PREP_BLKS, 256, 0, stream>>>(Wself1, Wneigh1, Bt1,
                                            Wself2, Wneigh2, Bt2, Wp1, Wp1b, deg_i);

    // -------- CSR build --------
    deg_count<<<(NE + 255) / 256, 256, 0, stream>>>(edst, deg_i);
    scan_part<<<NBLK_SCAN, 256, 0, stream>>>(deg_i, off, bsums);
    scan_sums<<<1, 256, 0, stream>>>(bsums, boff);
    scan_add<<<NBLK_SCAN, 256, 0, stream>>>(off, boff, cursor);
    fill_csr<<<(NE + 255) / 256, 256, 0, stream>>>(esrc, edst, cursor, eidx);

    // -------- layer 1: fused cvt+GEMM (R9-exact, XCD swizzle) --------
    int nwg1 = (512 / 128) * ((NN + 127) / 128);   // 4 * 391 = 1564
    gemm_xf32<<<nwg1, 256, 0, stream>>>(x, Bt1, C1b, NN, 512, DIN);
    agg_combine256<<<(NN + 3) / 4, 256, 0, stream>>>(C1b, off, eidx, b1, h1b);

    // -------- layer 2 (bf16 C2) --------
    int nwg2 = (128 / 128) * ((NN + 127) / 128);   // 391
    gemm_bf16<<<nwg2, 256, 0, stream>>>(h1b, Bt2, C2b, NN, 128, DH);
    agg_combine64<<<(NN + 3) / 4, 256, 0, stream>>>(C2b, off, eidx, b2, h2b);

    // -------- edge scorer (MFMA) --------
    edge_mlp_mfma<<<(2 * NP + 127) / 128, 256, 0, stream>>>(h2b, psrc, pdst, nsrc, ndst,
                                                            Wp1b, bp1, Wp2, bp2, out);
}

// Round 16
// 167.614 us; speedup vs baseline: 1.1685x; 1.0131x over previous
//
#include <hip/hip_runtime.h>

#define NN 50000      // nodes
#define NE 160000     // graph edges
#define NP 100000     // pos (=neg) edges
#define DIN 512
#define DH  256
#define DO  64
#define NBLK_SCAN 196 // ceil(50000/256)

// prep_all block-range partition (weights + deg zero only)
#define PW1_BLKS 1024    // 512*512 / 256
#define PW2_BLKS 128     // 128*256 / 256
#define PWP_BLKS 32      // 64*128 / 256
#define ZDEG_BLKS 196    // 50048 / 256
#define PREP_BLKS (PW1_BLKS + PW2_BLKS + PWP_BLKS + ZDEG_BLKS)

typedef short bf16x8 __attribute__((ext_vector_type(8)));
typedef float f32x4  __attribute__((ext_vector_type(4)));

__device__ __forceinline__ float bf2f(unsigned short u) {
    return __uint_as_float(((unsigned int)u) << 16);
}
__device__ __forceinline__ unsigned short f2bf(float f) {
    unsigned int x = __float_as_uint(f);
    return (unsigned short)((x + 0x7fffu + ((x >> 16) & 1u)) >> 16);
}

__device__ __forceinline__ void gload_lds16(const void* g, void* l) {
    __builtin_amdgcn_global_load_lds(
        (const __attribute__((address_space(1))) void*)g,
        (__attribute__((address_space(3))) void*)l, 16, 0, 0);
}

// ---------------- fused prep: cvt+transpose weights, zero deg ----------
__global__ __launch_bounds__(256) void prep_all(
    const float* __restrict__ Wself1, const float* __restrict__ Wneigh1, unsigned short* __restrict__ Bt1,
    const float* __restrict__ Wself2, const float* __restrict__ Wneigh2, unsigned short* __restrict__ Bt2,
    const float* __restrict__ Wp1, unsigned short* __restrict__ Wp1b,
    int* __restrict__ deg_i)
{
    int blk = blockIdx.x;
    if (blk < PW1_BLKS) {
        int idx = blk * 256 + threadIdx.x;
        int n = idx >> 9, k = idx & 511;
        float v = (n < DH) ? Wself1[(size_t)k * DH + n] : Wneigh1[(size_t)k * DH + (n - DH)];
        Bt1[idx] = f2bf(v);
        return;
    }
    blk -= PW1_BLKS;
    if (blk < PW2_BLKS) {
        int idx = blk * 256 + threadIdx.x;
        int n = idx >> 8, k = idx & 255;
        float v = (n < DO) ? Wself2[(size_t)k * DO + n] : Wneigh2[(size_t)k * DO + (n - DO)];
        Bt2[idx] = f2bf(v);
        return;
    }
    blk -= PW2_BLKS;
    if (blk < PWP_BLKS) {
        int idx = blk * 256 + threadIdx.x;
        int n = idx >> 7, k = idx & 127;
        Wp1b[idx] = f2bf(Wp1[(size_t)k * 64 + n]);
        return;
    }
    blk -= PWP_BLKS;
    {
        int i = blk * 256 + threadIdx.x;
        if (i < 50048) deg_i[i] = 0;
    }
}

// ---------------- CSR build ----------------
__global__ __launch_bounds__(256) void deg_count(const int* __restrict__ dst, int* __restrict__ deg) {
    int e = blockIdx.x * 256 + threadIdx.x;
    if (e < NE) atomicAdd(&deg[dst[e]], 1);
}

__global__ __launch_bounds__(256) void scan_part(const int* __restrict__ deg, int* __restrict__ excl,
                                                 int* __restrict__ bsums) {
    __shared__ int sh[256];
    int i = blockIdx.x * 256 + threadIdx.x;
    int v = (i < NN) ? deg[i] : 0;
    sh[threadIdx.x] = v;
    __syncthreads();
    #pragma unroll
    for (int off = 1; off < 256; off <<= 1) {
        int t = (threadIdx.x >= off) ? sh[threadIdx.x - off] : 0;
        __syncthreads();
        sh[threadIdx.x] += t;
        __syncthreads();
    }
    if (i < NN) excl[i] = sh[threadIdx.x] - v;
    if (threadIdx.x == 255) bsums[blockIdx.x] = sh[255];
}

__global__ __launch_bounds__(256) void scan_sums(int* __restrict__ bsums, int* __restrict__ boff) {
    __shared__ int sh[256];
    int v = (threadIdx.x < NBLK_SCAN) ? bsums[threadIdx.x] : 0;
    sh[threadIdx.x] = v;
    __syncthreads();
    #pragma unroll
    for (int off = 1; off < 256; off <<= 1) {
        int t = (threadIdx.x >= off) ? sh[threadIdx.x - off] : 0;
        __syncthreads();
        sh[threadIdx.x] += t;
        __syncthreads();
    }
    boff[threadIdx.x] = sh[threadIdx.x] - v;
}

__global__ __launch_bounds__(256) void scan_add(int* __restrict__ off, const int* __restrict__ boff,
                                                int* __restrict__ cursor) {
    int i = blockIdx.x * 256 + threadIdx.x;
    if (i < NN) {
        int o = off[i] + boff[blockIdx.x];
        off[i] = o;
        cursor[i] = o;
    }
    if (i == 0) off[NN] = NE;
}

__global__ __launch_bounds__(256) void fill_csr(const int* __restrict__ src, const int* __restrict__ dst,
                                                int* __restrict__ cursor, int* __restrict__ eidx) {
    int e = blockIdx.x * 256 + threadIdx.x;
    if (e < NE) {
        int p = atomicAdd(&cursor[dst[e]], 1);
        eidx[p] = src[e];
    }
}

// ---------------- layer-1 GEMM: C = cvt_bf16(x_f32) @ Bt1^T ------------------
// B-only double buffer, all-__syncthreads family (every barrier = full drain,
// no counted-vmcnt). Iteration: STAGE_B(t+1)->Bs[^1] issued BEFORE MFMA(t) so
// its drain at barrier-1 hides under compute; A-write (cvt of pa regs) moved
// after barrier-1; pa prefetch after barrier-2 hides under next MFMA.
// Hazards: every LDS write/read pair separated by >=1 full barrier.
// LDS 48 KB. 1D grid + bijective XCD-chunk swizzle (m204).
__global__ __launch_bounds__(256) void gemm_xf32(
    const float* __restrict__ A, const unsigned short* __restrict__ Bt,
    unsigned short* __restrict__ Cout, int M, int N, int K)
{
    __shared__ unsigned short As[128 * 64];        // 16 KB, single buffer
    __shared__ unsigned short Bs[2][128 * 64];     // 32 KB, double buffer
    const int tid = threadIdx.x;
    const int w = tid >> 6, l = tid & 63;
    const int wr = (w >> 1) * 64, wc = (w & 1) * 64;

    const int nwg = gridDim.x, gx = N >> 7;
    const int q = nwg >> 3, r = nwg & 7;
    const int xcd = blockIdx.x & 7, pos = blockIdx.x >> 3;
    const int work = (xcd < r ? xcd * (q + 1) : r * (q + 1) + (xcd - r) * q) + pos;
    const int row0 = (work / gx) * 128, col0 = (work % gx) * 128;

    const int NT = K >> 6;   // 8 K-tiles

    f32x4 acc[4][4];
    #pragma unroll
    for (int i = 0; i < 4; ++i)
        #pragma unroll
        for (int j = 0; j < 4; ++j)
            #pragma unroll
            for (int rr = 0; rr < 4; ++rr) acc[i][j][rr] = 0.0f;

    const int wave_lds_chunk = (tid & 192) * 8;

    float4 pa[4][2];   // per-thread A staging regs

#define LOAD_PA(K0)                                                          \
    {                                                                        \
        _Pragma("unroll")                                                    \
        for (int u = 0; u < 4; ++u) {                                        \
            int c = u * 256 + tid;                                           \
            int row_ = c >> 3, j_ = c & 7;                                   \
            int grow = row0 + row_; if (grow >= M) grow = M - 1;             \
            const float* s = A + (size_t)grow * K + (K0) + j_ * 8;           \
            pa[u][0] = *(const float4*)s;                                    \
            pa[u][1] = *(const float4*)(s + 4);                              \
        }                                                                    \
    }

#define WRITE_A()                                                            \
    {                                                                        \
        _Pragma("unroll")                                                    \
        for (int u = 0; u < 4; ++u) {                                        \
            int c = u * 256 + tid;                                           \
            int row_ = c >> 3, j_ = c & 7;                                   \
            int js_ = j_ ^ (row_ & 7);                                       \
            union { bf16x8 v; unsigned int u32[4]; } pk;                     \
            asm("v_cvt_pk_bf16_f32 %0, %1, %2" : "=v"(pk.u32[0]) : "v"(pa[u][0].x), "v"(pa[u][0].y)); \
            asm("v_cvt_pk_bf16_f32 %0, %1, %2" : "=v"(pk.u32[1]) : "v"(pa[u][0].z), "v"(pa[u][0].w)); \
            asm("v_cvt_pk_bf16_f32 %0, %1, %2" : "=v"(pk.u32[2]) : "v"(pa[u][1].x), "v"(pa[u][1].y)); \
            asm("v_cvt_pk_bf16_f32 %0, %1, %2" : "=v"(pk.u32[3]) : "v"(pa[u][1].z), "v"(pa[u][1].w)); \
            *(bf16x8*)&As[row_ * 64 + js_ * 8] = pk.v;                       \
        }                                                                    \
    }

#define STAGE_B(BUF, K0)                                                     \
    {                                                                        \
        _Pragma("unroll")                                                    \
        for (int u = 0; u < 4; ++u) {                                        \
            int c = u * 256 + tid;                                           \
            int cn_ = c >> 3, j_ = c & 7;                                    \
            int js_ = j_ ^ (cn_ & 7);                                        \
            gload_lds16(Bt + (size_t)(col0 + cn_) * K + (K0) + js_ * 8,      \
                        (void*)(Bs[BUF] + (u * 256) * 8 + wave_lds_chunk));  \
        }                                                                    \
    }

    // ---- prologue: A(0)+B(0) staged; pa = A(1) ----
    LOAD_PA(0);
    STAGE_B(0, 0);
    WRITE_A();           // consumes pa = A(0)
    LOAD_PA(64);         // pa = A(1)
    __syncthreads();     // drains B(0), A(0) writes, pa(1) loads (one-time cost)

    for (int t = 0; t < NT; ++t) {
        if (t + 1 < NT) STAGE_B((t + 1) & 1, (t + 1) * 64);   // hidden under MFMA(t)

        #pragma unroll
        for (int kk = 0; kk < 2; ++kk) {
            bf16x8 af[4], bfv[4];
            #pragma unroll
            for (int i = 0; i < 4; ++i) {
                int row = wr + i * 16 + (l & 15);
                int ch = (kk * 4 + (l >> 4)) ^ (row & 7);
                af[i] = *(const bf16x8*)&As[row * 64 + ch * 8];
            }
            #pragma unroll
            for (int j = 0; j < 4; ++j) {
                int cc = wc + j * 16 + (l & 15);
                int ch = (kk * 4 + (l >> 4)) ^ (cc & 7);
                bfv[j] = *(const bf16x8*)&Bs[t & 1][cc * 64 + ch * 8];
            }
            #pragma unroll
            for (int i = 0; i < 4; ++i)
                #pragma unroll
                for (int j = 0; j < 4; ++j)
                    acc[i][j] = __builtin_amdgcn_mfma_f32_16x16x32_bf16(af[i], bfv[j], acc[i][j], 0, 0, 0);
        }
        __syncthreads();   // drains B(t+1) [hidden under MFMA]; As/Bs reads done

        if (t + 1 < NT) {
            WRITE_A();                 // consumes pa = A(t+1) -> As (reads of A(t) done)
            __syncthreads();           // drains A ds_writes (lgkm only — fast)
            if (t + 2 < NT) LOAD_PA((t + 2) * 64);   // drained at next barrier-1, hidden
        }
    }
#undef LOAD_PA
#undef WRITE_A
#undef STAGE_B

    #pragma unroll
    for (int i = 0; i < 4; ++i) {
        #pragma unroll
        for (int j = 0; j < 4; ++j) {
            int r0 = row0 + wr + i * 16 + ((l >> 4) << 2);
            int c  = col0 + wc + j * 16 + (l & 15);
            #pragma unroll
            for (int rr = 0; rr < 4; ++rr) {
                if (r0 + rr < M)
                    Cout[(size_t)(r0 + rr) * N + c] = f2bf(acc[i][j][rr]);
            }
        }
    }
}

// ---------------- bf16 MFMA GEMM (layer 2): A bf16, Bt bf16, bf16 out --------
__global__ __launch_bounds__(256) void gemm_bf16(
    const unsigned short* __restrict__ A, const unsigned short* __restrict__ Bt,
    unsigned short* __restrict__ Cout, int M, int N, int K)
{
    __shared__ unsigned short As[128 * 64];
    __shared__ unsigned short Bs[128 * 64];
    const int tid = threadIdx.x;
    const int w = tid >> 6, l = tid & 63;
    const int wr = (w >> 1) * 64, wc = (w & 1) * 64;

    const int nwg = gridDim.x, gx = N >> 7;
    const int q = nwg >> 3, r = nwg & 7;
    const int xcd = blockIdx.x & 7, pos = blockIdx.x >> 3;
    const int work = (xcd < r ? xcd * (q + 1) : r * (q + 1) + (xcd - r) * q) + pos;
    const int row0 = (work / gx) * 128, col0 = (work % gx) * 128;

    f32x4 acc[4][4];
    #pragma unroll
    for (int i = 0; i < 4; ++i)
        #pragma unroll
        for (int j = 0; j < 4; ++j)
            #pragma unroll
            for (int rr = 0; rr < 4; ++rr) acc[i][j][rr] = 0.0f;

    const int wave_lds_chunk = (tid & 192) * 8;

    for (int k0 = 0; k0 < K; k0 += 64) {
        __syncthreads();
        #pragma unroll
        for (int u = 0; u < 4; ++u) {
            int c = u * 256 + tid;
            int row = c >> 3, j = c & 7;
            int js = j ^ (row & 7);
            int grow = row0 + row; if (grow >= M) grow = M - 1;
            gload_lds16(A + (size_t)grow * K + k0 + js * 8,
                        (void*)(As + (u * 256) * 8 + wave_lds_chunk));
        }
        #pragma unroll
        for (int u = 0; u < 4; ++u) {
            int c = u * 256 + tid;
            int cn = c >> 3, j = c & 7;
            int js = j ^ (cn & 7);
            gload_lds16(Bt + (size_t)(col0 + cn) * K + k0 + js * 8,
                        (void*)(Bs + (u * 256) * 8 + wave_lds_chunk));
        }
        __syncthreads();

        #pragma unroll
        for (int kk = 0; kk < 2; ++kk) {
            bf16x8 af[4], bfv[4];
            #pragma unroll
            for (int i = 0; i < 4; ++i) {
                int row = wr + i * 16 + (l & 15);
                int ch = (kk * 4 + (l >> 4)) ^ (row & 7);
                af[i] = *(const bf16x8*)&As[row * 64 + ch * 8];
            }
            #pragma unroll
            for (int j = 0; j < 4; ++j) {
                int cc = wc + j * 16 + (l & 15);
                int ch = (kk * 4 + (l >> 4)) ^ (cc & 7);
                bfv[j] = *(const bf16x8*)&Bs[cc * 64 + ch * 8];
            }
            #pragma unroll
            for (int i = 0; i < 4; ++i)
                #pragma unroll
                for (int j = 0; j < 4; ++j)
                    acc[i][j] = __builtin_amdgcn_mfma_f32_16x16x32_bf16(af[i], bfv[j], acc[i][j], 0, 0, 0);
        }
    }

    #pragma unroll
    for (int i = 0; i < 4; ++i) {
        #pragma unroll
        for (int j = 0; j < 4; ++j) {
            int r0 = row0 + wr + i * 16 + ((l >> 4) << 2);
            int c  = col0 + wc + j * 16 + (l & 15);
            #pragma unroll
            for (int rr = 0; rr < 4; ++rr) {
                if (r0 + rr < M)
                    Cout[(size_t)(r0 + rr) * N + c] = f2bf(acc[i][j][rr]);
            }
        }
    }
}

// ---------------- gather-aggregate + combine, layer 1 (bf16 in/out, relu) ----
__global__ __launch_bounds__(256) void agg_combine256(
    const unsigned short* __restrict__ C1, const int* __restrict__ off, const int* __restrict__ eidx,
    const float* __restrict__ b, unsigned short* __restrict__ h1b)
{
    const int wave = threadIdx.x >> 6, lane = threadIdx.x & 63;
    const int n = blockIdx.x * 4 + wave;
    if (n >= NN) return;
    const int e0 = off[n], e1 = off[n + 1];
    float acc0 = 0.f, acc1 = 0.f, acc2 = 0.f, acc3 = 0.f;
    int e = e0;
    for (; e + 1 < e1; e += 2) {
        int s0 = eidx[e], s1 = eidx[e + 1];
        ushort4 v0 = *(const ushort4*)&C1[(size_t)s0 * 512 + 256 + lane * 4];
        ushort4 v1 = *(const ushort4*)&C1[(size_t)s1 * 512 + 256 + lane * 4];
        acc0 += bf2f(v0.x) + bf2f(v1.x);
        acc1 += bf2f(v0.y) + bf2f(v1.y);
        acc2 += bf2f(v0.z) + bf2f(v1.z);
        acc3 += bf2f(v0.w) + bf2f(v1.w);
    }
    if (e < e1) {
        int s0 = eidx[e];
        ushort4 v0 = *(const ushort4*)&C1[(size_t)s0 * 512 + 256 + lane * 4];
        acc0 += bf2f(v0.x); acc1 += bf2f(v0.y); acc2 += bf2f(v0.z); acc3 += bf2f(v0.w);
    }
    const float rd = (e1 > e0) ? 1.0f / (float)(e1 - e0) : 1.0f;
    ushort4 sv = *(const ushort4*)&C1[(size_t)n * 512 + lane * 4];
    float4 bb = ((const float4*)b)[lane];
    ushort4 o;
    o.x = f2bf(fmaxf(bf2f(sv.x) + acc0 * rd + bb.x, 0.f));
    o.y = f2bf(fmaxf(bf2f(sv.y) + acc1 * rd + bb.y, 0.f));
    o.z = f2bf(fmaxf(bf2f(sv.z) + acc2 * rd + bb.z, 0.f));
    o.w = f2bf(fmaxf(bf2f(sv.w) + acc3 * rd + bb.w, 0.f));
    *(ushort4*)&h1b[(size_t)n * 256 + lane * 4] = o;
}

// ---------------- gather-aggregate + combine, layer 2 (bf16 in, bf16 out) ----
__global__ __launch_bounds__(256) void agg_combine64(
    const unsigned short* __restrict__ C2, const int* __restrict__ off, const int* __restrict__ eidx,
    const float* __restrict__ b, unsigned short* __restrict__ h2b)
{
    const int wave = threadIdx.x >> 6, lane = threadIdx.x & 63;
    const int n = blockIdx.x * 4 + wave;
    if (n >= NN) return;
    const int e0 = off[n], e1 = off[n + 1];
    float acc = 0.f;
    int e = e0;
    for (; e + 1 < e1; e += 2) {
        int s0 = eidx[e], s1 = eidx[e + 1];
        float v0 = bf2f(C2[(size_t)s0 * 128 + 64 + lane]);
        float v1 = bf2f(C2[(size_t)s1 * 128 + 64 + lane]);
        acc += v0 + v1;
    }
    if (e < e1) acc += bf2f(C2[(size_t)eidx[e] * 128 + 64 + lane]);
    const float rd = (e1 > e0) ? 1.0f / (float)(e1 - e0) : 1.0f;
    h2b[(size_t)n * 64 + lane] = f2bf(bf2f(C2[(size_t)n * 128 + lane]) + acc * rd + b[lane]);
}

// ---------------- edge MLP via MFMA ----------------
__global__ __launch_bounds__(256) void edge_mlp_mfma(
    const unsigned short* __restrict__ h2b,
    const int* __restrict__ psrc, const int* __restrict__ pdst,
    const int* __restrict__ nsrc, const int* __restrict__ ndst,
    const unsigned short* __restrict__ Wp1b, const float* __restrict__ bp1,
    const float* __restrict__ Wp2, const float* __restrict__ bp2,
    float* __restrict__ out)
{
    __shared__ unsigned short z[128 * 128];
    const int tid = threadIdx.x;
    const int w = tid >> 6, l = tid & 63;
    const int e0 = blockIdx.x * 128;

    bf16x8 bfr[4][4];
    #pragma unroll
    for (int kk = 0; kk < 4; ++kk)
        #pragma unroll
        for (int j = 0; j < 4; ++j) {
            int col = j * 16 + (l & 15);
            int ch  = kk * 4 + (l >> 4);
            bfr[kk][j] = *(const bf16x8*)(Wp1b + col * 128 + ch * 8);
        }

    #pragma unroll
    for (int p = 0; p < 8; ++p) {
        int rho = p * 32 + (tid >> 3);
        int c   = tid & 7;
        int r   = rho >> 1;
        int ep  = rho & 1;
        int e   = e0 + r; if (e >= 2 * NP) e = 2 * NP - 1;
        int node = (e < NP) ? (ep ? pdst[e] : psrc[e])
                            : (ep ? ndst[e - NP] : nsrc[e - NP]);
        bf16x8 v = *(const bf16x8*)(h2b + (size_t)node * 64 + c * 8);
        int j = ep * 8 + c;
        *(bf16x8*)&z[r * 128 + ((j ^ (r & 15)) * 8)] = v;
    }
    __syncthreads();

    f32x4 acc[2][4];
    #pragma unroll
    for (int i = 0; i < 2; ++i)
        #pragma unroll
        for (int j = 0; j < 4; ++j)
            #pragma unroll
            for (int rr = 0; rr < 4; ++rr) acc[i][j][rr] = 0.0f;

    #pragma unroll
    for (int kk = 0; kk < 4; ++kk) {
        bf16x8 af[2];
        #pragma unroll
        for (int i = 0; i < 2; ++i) {
            int row = w * 32 + i * 16 + (l & 15);
            int ch  = (kk * 4 + (l >> 4)) ^ (row & 15);
            af[i] = *(const bf16x8*)&z[row * 128 + ch * 8];
        }
        #pragma unroll
        for (int i = 0; i < 2; ++i)
            #pragma unroll
            for (int j = 0; j < 4; ++j)
                acc[i][j] = __builtin_amdgcn_mfma_f32_16x16x32_bf16(af[i], bfr[kk][j], acc[i][j], 0, 0, 0);
    }

    float bp1v[4], w2v[4];
    #pragma unroll
    for (int j = 0; j < 4; ++j) {
        bp1v[j] = bp1[j * 16 + (l & 15)];
        w2v[j]  = Wp2[j * 16 + (l & 15)];
    }
    const float b2v = bp2[0];
    #pragma unroll
    for (int i = 0; i < 2; ++i) {
        #pragma unroll
        for (int rr = 0; rr < 4; ++rr) {
            float p = 0.f;
            #pragma unroll
            for (int j = 0; j < 4; ++j) {
                float h = fmaxf(acc[i][j][rr] + bp1v[j], 0.f);
                p = fmaf(h, w2v[j], p);
            }
            #pragma unroll
            for (int off = 8; off > 0; off >>= 1)
                p += __shfl_xor(p, off, 64);
            int row = w * 32 + i * 16 + ((l >> 4) << 2) + rr;
            if ((l & 15) == 0 && e0 + row < 2 * NP)
                out[e0 + row] = p + b2v;
        }
    }
}

extern "C" void kernel_launch(void* const* d_in, const int* in_sizes, int n_in,
                              void* d_out, int out_size, void* d_ws, size_t ws_size,
                              hipStream_t stream) {
    (void)in_sizes; (void)n_in; (void)out_size; (void)ws_size;
    const float* x       = (const float*)d_in[0];
    const int*   esrc    = (const int*)d_in[1];
    const int*   edst    = (const int*)d_in[2];
    const int*   psrc    = (const int*)d_in[3];
    const int*   pdst    = (const int*)d_in[4];
    const int*   nsrc    = (const int*)d_in[5];
    const int*   ndst    = (const int*)d_in[6];
    const float* Wself1  = (const float*)d_in[7];
    const float* Wneigh1 = (const float*)d_in[8];
    const float* b1      = (const float*)d_in[9];
    const float* Wself2  = (const float*)d_in[10];
    const float* Wneigh2 = (const float*)d_in[11];
    const float* b2      = (const float*)d_in[12];
    const float* Wp1     = (const float*)d_in[13];
    const float* bp1     = (const float*)d_in[14];
    const float* Wp2     = (const float*)d_in[15];
    const float* bp2     = (const float*)d_in[16];
    float* out = (float*)d_out;

    // -------- workspace carve-up --------
    char* w = (char*)d_ws;
    int* deg_i  = (int*)w; w += 50048 * 4;
    int* off    = (int*)w; w += 50052 * 4;
    int* cursor = (int*)w; w += 50048 * 4;
    int* bsums  = (int*)w; w += 256 * 4;
    int* boff   = (int*)w; w += 256 * 4;
    int* eidx   = (int*)w; w += 160000 * 4;
    unsigned short* Bt1  = (unsigned short*)w; w += (size_t)512 * 512 * 2;
    unsigned short* Bt2  = (unsigned short*)w; w += (size_t)128 * 256 * 2;
    unsigned short* Wp1b = (unsigned short*)w; w += (size_t)64 * 128 * 2;
    unsigned short* h1b  = (unsigned short*)w; w += (size_t)NN * DH * 2;   // 25.6 MB
    unsigned short* h2b  = (unsigned short*)w; w += (size_t)NN * DO * 2;   // 6.4 MB
    unsigned short* C1b  = (unsigned short*)w; w += (size_t)NN * 512 * 2;  // 51.2 MB
    unsigned short* C2b  = C1b;   // C1b dead after agg1; C2b = 12.8 MB bf16

    // -------- fused prep (weights, zero deg) --------
    prep_all<<<PREP_BLKS, 256, 0, stream>>>(Wself1, Wneigh1, Bt1,
                                            Wself2, Wneigh2, Bt2, Wp1, Wp1b, deg_i);

    // -------- CSR build --------
    deg_count<<<(NE + 255) / 256, 256, 0, stream>>>(edst, deg_i);
    scan_part<<<NBLK_SCAN, 256, 0, stream>>>(deg_i, off, bsums);
    scan_sums<<<1, 256, 0, stream>>>(bsums, boff);
    scan_add<<<NBLK_SCAN, 256, 0, stream>>>(off, boff, cursor);
    fill_csr<<<(NE + 255) / 256, 256, 0, stream>>>(esrc, edst, cursor, eidx);

    // -------- layer 1: fused cvt+GEMM (B-dbuf hidden-stage, XCD swizzle) ------
    int nwg1 = (512 / 128) * ((NN + 127) / 128);   // 4 * 391 = 1564
    gemm_xf32<<<nwg1, 256, 0, stream>>>(x, Bt1, C1b, NN, 512, DIN);
    agg_combine256<<<(NN + 3) / 4, 256, 0, stream>>>(C1b, off, eidx, b1, h1b);

    // -------- layer 2 (bf16 C2) --------
    int nwg2 = (128 / 128) * ((NN + 127) / 128);   // 391
    gemm_bf16<<<nwg2, 256, 0, stream>>>(h1b, Bt2, C2b, NN, 128, DH);
    agg_combine64<<<(NN + 3) / 4, 256, 0, stream>>>(C2b, off, eidx, b2, h2b);

    // -------- edge scorer (MFMA) --------
    edge_mlp_mfma<<<(2 * NP + 127) / 128, 256, 0, stream>>>(h2b, psrc, pdst, nsrc, ndst,
                                                            Wp1b, bp1, Wp2, bp2, out);
}